// Round 1
// baseline (17946.397 us; speedup 1.0000x reference)
//
#include <hip/hip_runtime.h>
#include <math.h>

// Problem constants
#define BB   2048   // batch
#define NN_  768    // signal dim (n)
#define MM   3072   // atoms (m)
#define LAMBD 0.1f

// ---------------------------------------------------------------------------
// Tiled fp32 GEMM, 64x64 tile, BK=16, 256 threads, 4x4 per thread.
// LAYA: 0 = N (a[i*lda+k]), 1 = T (a[k*lda+i])
// LAYB: 0 = N (b[k*ldb+j]), 1 = T (b[j*ldb+k])
// EPI : 0 = store C=acc
//       1 = store C=acc + I (identity add, for G)
//       2 = store C = 2*E1 - acc   (Newton-Schulz)
//       3 = ADMM x-update: E1=adotb, C=v (in/out), E3=u (in/out)
// FUSEA: A element = A + E1 - E2 (y = adotb + v - u), layout N only
// ---------------------------------------------------------------------------
template<int LAYA, int LAYB, int EPI, int FUSEA>
__global__ __launch_bounds__(256)
void gemm64(const float* __restrict__ A, int lda,
            const float* __restrict__ B, int ldb,
            float* __restrict__ C, int ldc,
            int K,
            const float* __restrict__ E1,
            const float* __restrict__ E2,
            float* __restrict__ E3)
{
    __shared__ float As[16][65];
    __shared__ float Bs[16][65];
    const int tid  = threadIdx.x;
    const int brow = blockIdx.y * 64;
    const int bcol = blockIdx.x * 64;
    const int ty = tid >> 4, tx = tid & 15;

    float acc[4][4] = {};

    for (int k0 = 0; k0 < K; k0 += 16) {
        // ---- load A tile into As[k][i] ----
        if (LAYA == 0) {
            const int i  = tid >> 2;
            const int k4 = (tid & 3) * 4;
            const size_t g = (size_t)(brow + i) * lda + k0 + k4;
            float4 va = *(const float4*)(A + g);
            if (FUSEA) {
                float4 vv = *(const float4*)(E1 + g);
                float4 vu = *(const float4*)(E2 + g);
                va.x += vv.x - vu.x; va.y += vv.y - vu.y;
                va.z += vv.z - vu.z; va.w += vv.w - vu.w;
            }
            As[k4+0][i] = va.x; As[k4+1][i] = va.y;
            As[k4+2][i] = va.z; As[k4+3][i] = va.w;
        } else {
            const int k  = tid >> 4;
            const int i4 = (tid & 15) * 4;
            float4 va = *(const float4*)(A + (size_t)(k0 + k) * lda + brow + i4);
            As[k][i4+0] = va.x; As[k][i4+1] = va.y;
            As[k][i4+2] = va.z; As[k][i4+3] = va.w;
        }
        // ---- load B tile into Bs[k][j] ----
        if (LAYB == 0) {
            const int k  = tid >> 4;
            const int j4 = (tid & 15) * 4;
            float4 vb = *(const float4*)(B + (size_t)(k0 + k) * ldb + bcol + j4);
            Bs[k][j4+0] = vb.x; Bs[k][j4+1] = vb.y;
            Bs[k][j4+2] = vb.z; Bs[k][j4+3] = vb.w;
        } else {
            const int j  = tid >> 2;
            const int k4 = (tid & 3) * 4;
            float4 vb = *(const float4*)(B + (size_t)(bcol + j) * ldb + k0 + k4);
            Bs[k4+0][j] = vb.x; Bs[k4+1][j] = vb.y;
            Bs[k4+2][j] = vb.z; Bs[k4+3][j] = vb.w;
        }
        __syncthreads();

        #pragma unroll
        for (int kk = 0; kk < 16; ++kk) {
            float ar[4], bc[4];
            #pragma unroll
            for (int r = 0; r < 4; ++r) ar[r] = As[kk][ty*4 + r];
            #pragma unroll
            for (int c = 0; c < 4; ++c) bc[c] = Bs[kk][tx*4 + c];
            #pragma unroll
            for (int r = 0; r < 4; ++r)
                #pragma unroll
                for (int c = 0; c < 4; ++c)
                    acc[r][c] = fmaf(ar[r], bc[c], acc[r][c]);
        }
        __syncthreads();
    }

    // ---- epilogue ----
    #pragma unroll
    for (int r = 0; r < 4; ++r) {
        const int i = brow + ty*4 + r;
        #pragma unroll
        for (int c = 0; c < 4; ++c) {
            const int j = bcol + tx*4 + c;
            const size_t idx = (size_t)i * ldc + j;
            if (EPI == 0) {
                C[idx] = acc[r][c];
            } else if (EPI == 1) {
                C[idx] = acc[r][c] + (i == j ? 1.0f : 0.0f);
            } else if (EPI == 2) {
                C[idx] = 2.0f * E1[idx] - acc[r][c];
            } else { // EPI == 3: ADMM update. E1=adotb, C=v, E3=u
                const float uu = E3[idx];
                const float vv = C[idx];
                const float y  = E1[idx] + vv - uu;
                const float x  = y - acc[r][c];
                const float xu = x + uu;
                const float t  = fabsf(xu) - LAMBD;
                const float vn = (t > 0.0f) ? copysignf(t, xu) : 0.0f;
                C[idx]  = vn;
                E3[idx] = uu + x - vn;
            }
        }
    }
}

// Normalize rows of weight (3072 x 768) to unit L2 norm.
__global__ __launch_bounds__(256)
void rownorm_kernel(const float* __restrict__ W, float* __restrict__ Wn)
{
    __shared__ float red[256];
    const int row = blockIdx.x;
    const int t = threadIdx.x;
    const float* wr = W + (size_t)row * NN_;
    float s = 0.0f;
    for (int k = t; k < NN_; k += 256) { float w = wr[k]; s += w * w; }
    red[t] = s; __syncthreads();
    for (int off = 128; off > 0; off >>= 1) {
        if (t < off) red[t] += red[t + off];
        __syncthreads();
    }
    const float rn = 1.0f / sqrtf(red[0]);
    float* wo = Wn + (size_t)row * NN_;
    for (int k = t; k < NN_; k += 256) wo[k] = wr[k] * rn;
}

// Single-block power iteration on G (768x768) -> c = 2/(1 + 1.06*lambda_max)
__global__ void power_iter_kernel(const float* __restrict__ G, float* __restrict__ cout)
{
    __shared__ float v[NN_];
    __shared__ float red[NN_];
    const int t = threadIdx.x;
    v[t] = 1.0f;
    __syncthreads();
    float lam = 1.0f;
    for (int it = 0; it < 60; ++it) {
        float s = 0.0f;
        const float* gr = G + (size_t)t * NN_;
        for (int k = 0; k < NN_; ++k) s = fmaf(gr[k], v[k], s);
        red[t] = s * s;
        __syncthreads();
        for (int off = NN_ / 2; off > 0; off >>= 1) {
            if (t < off) red[t] += red[t + off];
            __syncthreads();
        }
        lam = sqrtf(red[0]);
        v[t] = s / lam;
        __syncthreads();
    }
    if (t == 0) cout[0] = 2.0f / (1.0f + 1.06f * lam);
}

// X = c * I  (768x768)
__global__ __launch_bounds__(256)
void initdiag_kernel(float* __restrict__ X, const float* __restrict__ c)
{
    const int idx = blockIdx.x * 256 + threadIdx.x;
    const int p = idx / NN_, q = idx - p * NN_;
    X[idx] = (p == q) ? c[0] : 0.0f;
}

extern "C" void kernel_launch(void* const* d_in, const int* in_sizes, int n_in,
                              void* d_out, int out_size, void* d_ws, size_t ws_size,
                              hipStream_t stream)
{
    const float* x = (const float*)d_in[0];   // (2048, 768) flat
    const float* w = (const float*)d_in[1];   // (3072, 768)

    float* out = (float*)d_out;
    float* z   = out;                          // (2048, 3072) = v
    float* dec = out + (size_t)BB * MM;        // (2048, 768)
    float* Tb  = dec;                          // reuse decoded region as T scratch

    float* ws = (float*)d_ws;
    size_t off = 0;
    float* wn    = ws + off; off += (size_t)MM * NN_;   // 3072x768
    float* adotb = ws + off; off += (size_t)BB * MM;    // 2048x3072
    float* u     = ws + off; off += (size_t)BB * MM;    // 2048x3072
    float* Ub    = ws + off; off += (size_t)BB * NN_;   // 2048x768
    float* G     = ws + off; off += (size_t)NN_ * NN_;
    float* Xa    = ws + off; off += (size_t)NN_ * NN_;
    float* Xb    = ws + off; off += (size_t)NN_ * NN_;
    float* Yb    = ws + off; off += (size_t)NN_ * NN_;
    float* cbuf  = ws + off; off += 4;

    hipMemsetAsync(u, 0, (size_t)BB * MM * sizeof(float), stream);
    hipMemsetAsync(z, 0, (size_t)BB * MM * sizeof(float), stream);

    const dim3 blk(256);

    // w_n = normalize rows
    rownorm_kernel<<<MM, blk, 0, stream>>>(w, wn);

    // adotb = x @ w_n^T   (2048x3072, K=768)   A:N  B:T
    gemm64<0,1,0,0><<<dim3(MM/64, BB/64), blk, 0, stream>>>(
        x, NN_, wn, NN_, adotb, MM, NN_, nullptr, nullptr, nullptr);

    // G = w_n^T w_n + I   (768x768, K=3072)    A:T  B:N
    gemm64<1,0,1,0><<<dim3(NN_/64, NN_/64), blk, 0, stream>>>(
        wn, NN_, wn, NN_, G, NN_, MM, nullptr, nullptr, nullptr);

    // lambda_max estimate -> c
    power_iter_kernel<<<1, NN_, 0, stream>>>(G, cbuf);
    initdiag_kernel<<<(NN_*NN_)/256, blk, 0, stream>>>(Xa, cbuf);

    // Newton-Schulz: X <- 2X - X G X   (9 iterations)
    for (int it = 0; it < 9; ++it) {
        gemm64<0,0,0,0><<<dim3(NN_/64, NN_/64), blk, 0, stream>>>(
            G, NN_, Xa, NN_, Yb, NN_, NN_, nullptr, nullptr, nullptr);
        gemm64<0,0,2,0><<<dim3(NN_/64, NN_/64), blk, 0, stream>>>(
            Xa, NN_, Yb, NN_, Xb, NN_, NN_, Xa, nullptr, nullptr);
        float* tmp = Xa; Xa = Xb; Xb = tmp;
    }
    // Q = Xa = G^{-1}

    // ADMM main loop (always 20 iterations; reference's early-exit tolerance
    // 1e-4 is not reached in 20 iters, and post-convergence iters are no-ops
    // within the output threshold anyway).
    for (int it = 0; it < 20; ++it) {
        // T = (adotb + v - u) @ w_n    (2048x768, K=3072)  A:N fused, B:N
        gemm64<0,0,0,1><<<dim3(NN_/64, BB/64), blk, 0, stream>>>(
            adotb, MM, wn, NN_, Tb, NN_, MM, z, u, nullptr);
        // U = T @ Q                    (2048x768, K=768)
        gemm64<0,0,0,0><<<dim3(NN_/64, BB/64), blk, 0, stream>>>(
            Tb, NN_, Xa, NN_, Ub, NN_, NN_, nullptr, nullptr, nullptr);
        // acc = U @ w_n^T; x = y - acc; v,u update fused  (2048x3072, K=768)
        gemm64<0,1,3,0><<<dim3(MM/64, BB/64), blk, 0, stream>>>(
            Ub, NN_, wn, NN_, z, MM, NN_, adotb, nullptr, u);
    }

    // decoded = z @ w_n   (2048x768, K=3072)
    gemm64<0,0,0,0><<<dim3(NN_/64, BB/64), blk, 0, stream>>>(
        z, MM, wn, NN_, dec, NN_, MM, nullptr, nullptr, nullptr);
}

// Round 3
// 5843.695 us; speedup vs baseline: 3.0711x; 3.0711x over previous
//
#include <hip/hip_runtime.h>
#include <math.h>

#define BB   2048
#define NN_  768
#define MM   3072
#define LAMBD 0.1f

typedef __attribute__((ext_vector_type(8))) short  short8;
typedef __attribute__((ext_vector_type(4))) float  f32x4;
typedef __attribute__((ext_vector_type(4))) unsigned short us4;

struct HL { unsigned short h, l; };

__device__ __forceinline__ unsigned short bf16rne(float f) {
    unsigned int u = __float_as_uint(f);
    u += 0x7FFFu + ((u >> 16) & 1u);
    return (unsigned short)(u >> 16);
}
__device__ __forceinline__ HL split2(float f) {
    HL r;
    r.h = bf16rne(f);
    const float fh = __uint_as_float(((unsigned int)r.h) << 16);
    r.l = bf16rne(f - fh);
    return r;
}

// ---------------------------------------------------------------------------
// Split-bf16 MFMA GEMM. C(M,N) = A(M,K) @ B(K,N) with fused epilogues.
// A: f32 in global (split hi/lo on the fly) unless APRE=1 (pre-split bf16,
//    row-major [i][k]).
// B: ALWAYS pre-split bf16 read as [col][k] rows (i.e. caller passes B^T
//    row-major; all our B matrices are symmetric or pre-transposed).
// FUSEA: A element = A + E1 - E2 (y = adotb + v - u)
// EPI: 0 plain, 1 +I, 2 C = 2*E1 - acc, 3 ADMM (E1=adotb, C=v io, E3=u io)
// SPLIT: also write bf16 hi/lo of result to Ch/Cl.
// Tile BM x BN, BK=32, 256 threads = 4 waves in 2x2, each wave BM/2 x BN/2.
// ---------------------------------------------------------------------------
template<int BM, int BN, int APRE, int FUSEA, int EPI, int SPLIT>
__global__ __launch_bounds__(256)
void gemm_mfma(const float* __restrict__ A,
               const unsigned short* __restrict__ Ah,
               const unsigned short* __restrict__ Al,
               int lda,
               const unsigned short* __restrict__ Bh,
               const unsigned short* __restrict__ Bl,
               int ldb,
               float* __restrict__ C, int ldc, int K,
               const float* __restrict__ E1,
               const float* __restrict__ E2,
               float* __restrict__ E3,
               unsigned short* __restrict__ Ch,
               unsigned short* __restrict__ Cl)
{
    constexpr int MF = BM / 32;   // frags per wave in M
    constexpr int NF = BN / 32;   // frags per wave in N
    // pad rows to 40 bf16 (80B): ds_read_b128 lands 2-way bank aliasing (free)
    __shared__ unsigned short AsH[BM][40], AsL[BM][40];
    __shared__ unsigned short BsH[BN][40], BsL[BN][40];

    const int tid  = threadIdx.x;
    const int brow = blockIdx.y * BM;
    const int bcol = blockIdx.x * BN;
    const int wave = tid >> 6, lane = tid & 63;
    const int wr = wave >> 1, wc = wave & 1;
    const int lrow = lane & 15, kg = lane >> 4;

    f32x4 acc[MF][NF];
    #pragma unroll
    for (int m = 0; m < MF; ++m)
        #pragma unroll
        for (int n = 0; n < NF; ++n)
            #pragma unroll
            for (int q = 0; q < 4; ++q) acc[m][n][q] = 0.0f;

    for (int k0 = 0; k0 < K; k0 += 32) {
        // ---- stage A tile: As[row][k] ----
        constexpr int NPA = BM * 8 / 256;
        #pragma unroll
        for (int p = 0; p < NPA; ++p) {
            const int idx = p * 256 + tid;
            const int row = idx >> 3, k4 = (idx & 7) << 2;
            const size_t g = (size_t)(brow + row) * lda + k0 + k4;
            if constexpr (APRE) {
                *(us4*)&AsH[row][k4] = *(const us4*)(Ah + g);
                *(us4*)&AsL[row][k4] = *(const us4*)(Al + g);
            } else {
                float4 va = *(const float4*)(A + g);
                if constexpr (FUSEA) {
                    const float4 vv = *(const float4*)(E1 + g);
                    const float4 vu = *(const float4*)(E2 + g);
                    va.x += vv.x - vu.x; va.y += vv.y - vu.y;
                    va.z += vv.z - vu.z; va.w += vv.w - vu.w;
                }
                const HL sx = split2(va.x), sy = split2(va.y);
                const HL sz = split2(va.z), sw = split2(va.w);
                us4 h, l;
                h.x = sx.h; l.x = sx.l; h.y = sy.h; l.y = sy.l;
                h.z = sz.h; l.z = sz.l; h.w = sw.h; l.w = sw.l;
                *(us4*)&AsH[row][k4] = h;
                *(us4*)&AsL[row][k4] = l;
            }
        }
        // ---- stage B tile: Bs[col][k] (B passed transposed/symmetric) ----
        constexpr int NPB = BN * 8 / 256;
        #pragma unroll
        for (int p = 0; p < NPB; ++p) {
            const int idx = p * 256 + tid;
            const int col = idx >> 3, k4 = (idx & 7) << 2;
            const size_t g = (size_t)(bcol + col) * ldb + k0 + k4;
            *(us4*)&BsH[col][k4] = *(const us4*)(Bh + g);
            *(us4*)&BsL[col][k4] = *(const us4*)(Bl + g);
        }
        __syncthreads();

        short8 ahi[MF], alo[MF], bhi[NF], blo[NF];
        #pragma unroll
        for (int m = 0; m < MF; ++m) {
            const int r = wr * (BM / 2) + m * 16 + lrow;
            ahi[m] = *(const short8*)&AsH[r][kg * 8];
            alo[m] = *(const short8*)&AsL[r][kg * 8];
        }
        #pragma unroll
        for (int n = 0; n < NF; ++n) {
            const int c = wc * (BN / 2) + n * 16 + lrow;
            bhi[n] = *(const short8*)&BsH[c][kg * 8];
            blo[n] = *(const short8*)&BsL[c][kg * 8];
        }
        #pragma unroll
        for (int m = 0; m < MF; ++m)
            #pragma unroll
            for (int n = 0; n < NF; ++n) {
                acc[m][n] = __builtin_amdgcn_mfma_f32_16x16x32_bf16(ahi[m], bhi[n], acc[m][n], 0, 0, 0);
                acc[m][n] = __builtin_amdgcn_mfma_f32_16x16x32_bf16(ahi[m], blo[n], acc[m][n], 0, 0, 0);
                acc[m][n] = __builtin_amdgcn_mfma_f32_16x16x32_bf16(alo[m], bhi[n], acc[m][n], 0, 0, 0);
            }
        __syncthreads();
    }

    // ---- epilogue: D frag layout col=lane&15, row=(lane>>4)*4+r ----
    #pragma unroll
    for (int m = 0; m < MF; ++m) {
        #pragma unroll
        for (int n = 0; n < NF; ++n) {
            #pragma unroll
            for (int r = 0; r < 4; ++r) {
                const int row = brow + wr * (BM / 2) + m * 16 + kg * 4 + r;
                const int col = bcol + wc * (BN / 2) + n * 16 + lrow;
                const size_t idx = (size_t)row * ldc + col;
                float v = acc[m][n][r];
                if constexpr (EPI == 1) v += (row == col) ? 1.0f : 0.0f;
                if constexpr (EPI == 2) v = 2.0f * E1[idx] - v;
                if constexpr (EPI == 3) {
                    const float uu = E3[idx];
                    const float vv = C[idx];
                    const float y  = E1[idx] + vv - uu;
                    const float x  = y - v;
                    const float xu = x + uu;
                    const float t  = fabsf(xu) - LAMBD;
                    const float vn = (t > 0.0f) ? copysignf(t, xu) : 0.0f;
                    C[idx]  = vn;
                    E3[idx] = uu + x - vn;
                } else {
                    C[idx] = v;
                }
                if constexpr (SPLIT) {
                    const HL s = split2(v);
                    Ch[idx] = s.h; Cl[idx] = s.l;
                }
            }
        }
    }
}

// Normalize rows of weight (3072 x 768); emit split-bf16 wn and wn^T.
__global__ __launch_bounds__(256)
void rownorm_kernel(const float* __restrict__ W,
                    unsigned short* __restrict__ wnH, unsigned short* __restrict__ wnL,
                    unsigned short* __restrict__ wnTH, unsigned short* __restrict__ wnTL)
{
    __shared__ float red[256];
    const int row = blockIdx.x;
    const int t = threadIdx.x;
    const float* wr = W + (size_t)row * NN_;
    float s = 0.0f;
    for (int k = t; k < NN_; k += 256) { const float w = wr[k]; s += w * w; }
    red[t] = s; __syncthreads();
    for (int off = 128; off > 0; off >>= 1) {
        if (t < off) red[t] += red[t + off];
        __syncthreads();
    }
    const float rn = 1.0f / sqrtf(red[0]);
    for (int k = t; k < NN_; k += 256) {
        const float v = wr[k] * rn;
        const HL s2 = split2(v);
        wnH[(size_t)row * NN_ + k] = s2.h;
        wnL[(size_t)row * NN_ + k] = s2.l;
        wnTH[(size_t)k * MM + row] = s2.h;
        wnTL[(size_t)k * MM + row] = s2.l;
    }
}

// Gershgorin: rowsum[i] = sum_j |G[i][j]|
__global__ __launch_bounds__(256)
void rowabs_kernel(const float* __restrict__ G, float* __restrict__ rowsum)
{
    __shared__ float red[256];
    const int row = blockIdx.x;
    const int t = threadIdx.x;
    const float* gr = G + (size_t)row * NN_;
    float s = 0.0f;
    for (int k = t; k < NN_; k += 256) s += fabsf(gr[k]);
    red[t] = s; __syncthreads();
    for (int off = 128; off > 0; off >>= 1) {
        if (t < off) red[t] += red[t + off];
        __syncthreads();
    }
    if (t == 0) rowsum[row] = red[0];
}

// c = 2 / (1 + max_i rowsum[i])   (bound >= lambda_max(G), NS-safe)
__global__ __launch_bounds__(256)
void cmax_kernel(const float* __restrict__ rowsum, float* __restrict__ cbuf)
{
    __shared__ float red[256];
    const int t = threadIdx.x;
    float mx = 0.0f;
    for (int k = t; k < NN_; k += 256) mx = fmaxf(mx, rowsum[k]);
    red[t] = mx; __syncthreads();
    for (int off = 128; off > 0; off >>= 1) {
        if (t < off) red[t] = fmaxf(red[t], red[t + off]);
        __syncthreads();
    }
    if (t == 0) cbuf[0] = 2.0f / (1.0f + red[0]);
}

// X0 = c * I
__global__ __launch_bounds__(256)
void initdiag_kernel(float* __restrict__ X, const float* __restrict__ c)
{
    const int idx = blockIdx.x * 256 + threadIdx.x;
    const int p = idx / NN_, q = idx - p * NN_;
    X[idx] = (p == q) ? c[0] : 0.0f;
}

extern "C" void kernel_launch(void* const* d_in, const int* in_sizes, int n_in,
                              void* d_out, int out_size, void* d_ws, size_t ws_size,
                              hipStream_t stream)
{
    const float* x = (const float*)d_in[0];   // (2048, 768)
    const float* w = (const float*)d_in[1];   // (3072, 768)

    float* out = (float*)d_out;
    float* z   = out;                          // (2048, 3072) = v
    float* dec = out + (size_t)BB * MM;        // (2048, 768)
    float* Tb  = dec;                          // T scratch reuses decoded region

    char* wsb = (char*)d_ws;
    size_t off = 0;
    auto alloc = [&](size_t bytes) -> void* {
        void* p = wsb + off;
        off += (bytes + 255) & ~(size_t)255;
        return p;
    };
    unsigned short* wnH  = (unsigned short*)alloc((size_t)MM * NN_ * 2);
    unsigned short* wnL  = (unsigned short*)alloc((size_t)MM * NN_ * 2);
    unsigned short* wnTH = (unsigned short*)alloc((size_t)MM * NN_ * 2);
    unsigned short* wnTL = (unsigned short*)alloc((size_t)MM * NN_ * 2);
    float* adotb = (float*)alloc((size_t)BB * MM * 4);
    float* u     = (float*)alloc((size_t)BB * MM * 4);
    float* Ub    = (float*)alloc((size_t)BB * NN_ * 4);
    float* G     = (float*)alloc((size_t)NN_ * NN_ * 4);
    unsigned short* GH  = (unsigned short*)alloc((size_t)NN_ * NN_ * 2);
    unsigned short* GL  = (unsigned short*)alloc((size_t)NN_ * NN_ * 2);
    float* X0 = (float*)alloc((size_t)NN_ * NN_ * 4);
    float* X1 = (float*)alloc((size_t)NN_ * NN_ * 4);
    float* Yb = (float*)alloc((size_t)NN_ * NN_ * 4);
    unsigned short* YbH = (unsigned short*)alloc((size_t)NN_ * NN_ * 2);
    unsigned short* YbL = (unsigned short*)alloc((size_t)NN_ * NN_ * 2);
    unsigned short* QH  = (unsigned short*)alloc((size_t)NN_ * NN_ * 2);
    unsigned short* QL  = (unsigned short*)alloc((size_t)NN_ * NN_ * 2);
    float* rowsum = (float*)alloc(NN_ * 4);
    float* cbuf   = (float*)alloc(256);

    (void)hipMemsetAsync(u, 0, (size_t)BB * MM * sizeof(float), stream);
    (void)hipMemsetAsync(z, 0, (size_t)BB * MM * sizeof(float), stream);

    const dim3 blk(256);

    rownorm_kernel<<<MM, blk, 0, stream>>>(w, wnH, wnL, wnTH, wnTL);

    // adotb = x @ wn^T : (2048x3072, K=768). B tile rows = wn rows.
    gemm_mfma<128,128,0,0,0,0><<<dim3(MM/128, BB/128), blk, 0, stream>>>(
        x, nullptr, nullptr, NN_, wnH, wnL, NN_, adotb, MM, NN_,
        nullptr, nullptr, nullptr, nullptr, nullptr);

    // G = wn^T wn + I : (768x768, K=3072). A = wnT (pre-split), B tile rows = wnT rows.
    gemm_mfma<64,64,1,0,1,1><<<dim3(NN_/64, NN_/64), blk, 0, stream>>>(
        nullptr, wnTH, wnTL, MM, wnTH, wnTL, MM, G, NN_, MM,
        nullptr, nullptr, nullptr, GH, GL);

    rowabs_kernel<<<NN_, blk, 0, stream>>>(G, rowsum);
    cmax_kernel<<<1, blk, 0, stream>>>(rowsum, cbuf);
    initdiag_kernel<<<(NN_ * NN_) / 256, blk, 0, stream>>>(X0, cbuf);

    // Newton-Schulz: X <- 2X - X G X (all operands symmetric / commuting)
    float* Xc = X0;
    float* Xn = X1;
    for (int it = 0; it < 9; ++it) {
        // Yb = Xc @ G
        gemm_mfma<64,64,0,0,0,1><<<dim3(NN_/64, NN_/64), blk, 0, stream>>>(
            Xc, nullptr, nullptr, NN_, GH, GL, NN_, Yb, NN_, NN_,
            nullptr, nullptr, nullptr, YbH, YbL);
        // Xn = 2*Xc - Xc @ Yb   (also emits Q hi/lo; last iter's wins)
        gemm_mfma<64,64,0,0,2,1><<<dim3(NN_/64, NN_/64), blk, 0, stream>>>(
            Xc, nullptr, nullptr, NN_, YbH, YbL, NN_, Xn, NN_, NN_,
            Xc, nullptr, nullptr, QH, QL);
        float* t = Xc; Xc = Xn; Xn = t;
    }

    // ADMM main loop, 20 iterations
    for (int it = 0; it < 20; ++it) {
        // T = (adotb + v - u) @ wn : (2048x768, K=3072). B tile rows = wnT rows.
        gemm_mfma<128,64,0,1,0,0><<<dim3(NN_/64, BB/128), blk, 0, stream>>>(
            adotb, nullptr, nullptr, MM, wnTH, wnTL, MM, Tb, NN_, MM,
            z, u, nullptr, nullptr, nullptr);
        // U = T @ Q : (2048x768, K=768). Q symmetric -> B tile rows = Q rows.
        gemm_mfma<128,64,0,0,0,0><<<dim3(NN_/64, BB/128), blk, 0, stream>>>(
            Tb, nullptr, nullptr, NN_, QH, QL, NN_, Ub, NN_, NN_,
            nullptr, nullptr, nullptr, nullptr, nullptr);
        // acc = U @ wn^T ; x = y - acc ; soft-shrink + dual fused : (2048x3072, K=768)
        gemm_mfma<128,128,0,0,3,0><<<dim3(MM/128, BB/128), blk, 0, stream>>>(
            Ub, nullptr, nullptr, NN_, wnH, wnL, NN_, z, MM, NN_,
            adotb, nullptr, u, nullptr, nullptr);
    }

    // decoded = z @ wn : (2048x768, K=3072)
    gemm_mfma<128,64,0,0,0,0><<<dim3(NN_/64, BB/128), blk, 0, stream>>>(
        z, nullptr, nullptr, MM, wnTH, wnTL, MM, dec, NN_, MM,
        nullptr, nullptr, nullptr, nullptr, nullptr);
}

// Round 4
// 3288.107 us; speedup vs baseline: 5.4580x; 1.7772x over previous
//
#include <hip/hip_runtime.h>
#include <math.h>

#define BB   2048
#define NN_  768
#define MM   3072
#define LAMBD 0.1f

typedef __attribute__((ext_vector_type(8))) short  short8;
typedef __attribute__((ext_vector_type(4))) float  f32x4;
typedef __attribute__((ext_vector_type(4))) unsigned short us4;

struct HL { unsigned short h, l; };

__device__ __forceinline__ unsigned short bf16rne(float f) {
    unsigned int u = __float_as_uint(f);
    u += 0x7FFFu + ((u >> 16) & 1u);
    return (unsigned short)(u >> 16);
}
__device__ __forceinline__ HL split2(float f) {
    HL r;
    r.h = bf16rne(f);
    const float fh = __uint_as_float(((unsigned int)r.h) << 16);
    r.l = bf16rne(f - fh);
    return r;
}
__device__ __forceinline__ float clampl(float x) {
    return fminf(fmaxf(x, -LAMBD), LAMBD);
}

// ---------------------------------------------------------------------------
// Small split-bf16 MFMA GEMM (kept from R3) — used for G and Newton-Schulz.
// 2D grid, no swizzle. EPI: 0 plain, 1 +I, 2 C=2*E1-acc. SPLIT: emit bf16 hi/lo.
// ---------------------------------------------------------------------------
template<int BM, int BN, int APRE, int EPI, int SPLIT>
__global__ __launch_bounds__(256)
void gemm_mfma(const float* __restrict__ A,
               const unsigned short* __restrict__ Ah,
               const unsigned short* __restrict__ Al,
               int lda,
               const unsigned short* __restrict__ Bh,
               const unsigned short* __restrict__ Bl,
               int ldb,
               float* __restrict__ C, int ldc, int K,
               const float* __restrict__ E1,
               unsigned short* __restrict__ Ch,
               unsigned short* __restrict__ Cl)
{
    constexpr int MF = BM / 32;
    constexpr int NF = BN / 32;
    __shared__ unsigned short AsH[BM][40], AsL[BM][40];
    __shared__ unsigned short BsH[BN][40], BsL[BN][40];

    const int tid  = threadIdx.x;
    const int brow = blockIdx.y * BM;
    const int bcol = blockIdx.x * BN;
    const int wave = tid >> 6, lane = tid & 63;
    const int wr = wave >> 1, wc = wave & 1;
    const int lrow = lane & 15, kg = lane >> 4;

    f32x4 acc[MF][NF];
    #pragma unroll
    for (int m = 0; m < MF; ++m)
        #pragma unroll
        for (int n = 0; n < NF; ++n)
            #pragma unroll
            for (int q = 0; q < 4; ++q) acc[m][n][q] = 0.0f;

    for (int k0 = 0; k0 < K; k0 += 32) {
        constexpr int NPA = BM * 8 / 256;
        #pragma unroll
        for (int p = 0; p < NPA; ++p) {
            const int idx = p * 256 + tid;
            const int row = idx >> 3, k4 = (idx & 7) << 2;
            const size_t g = (size_t)(brow + row) * lda + k0 + k4;
            if constexpr (APRE) {
                *(us4*)&AsH[row][k4] = *(const us4*)(Ah + g);
                *(us4*)&AsL[row][k4] = *(const us4*)(Al + g);
            } else {
                const float4 va = *(const float4*)(A + g);
                const HL sx = split2(va.x), sy = split2(va.y);
                const HL sz = split2(va.z), sw = split2(va.w);
                us4 h, l;
                h.x = sx.h; l.x = sx.l; h.y = sy.h; l.y = sy.l;
                h.z = sz.h; l.z = sz.l; h.w = sw.h; l.w = sw.l;
                *(us4*)&AsH[row][k4] = h;
                *(us4*)&AsL[row][k4] = l;
            }
        }
        constexpr int NPB = BN * 8 / 256;
        #pragma unroll
        for (int p = 0; p < NPB; ++p) {
            const int idx = p * 256 + tid;
            const int col = idx >> 3, k4 = (idx & 7) << 2;
            const size_t g = (size_t)(bcol + col) * ldb + k0 + k4;
            *(us4*)&BsH[col][k4] = *(const us4*)(Bh + g);
            *(us4*)&BsL[col][k4] = *(const us4*)(Bl + g);
        }
        __syncthreads();

        short8 ahi[MF], alo[MF], bhi[NF], blo[NF];
        #pragma unroll
        for (int m = 0; m < MF; ++m) {
            const int r = wr * (BM / 2) + m * 16 + lrow;
            ahi[m] = *(const short8*)&AsH[r][kg * 8];
            alo[m] = *(const short8*)&AsL[r][kg * 8];
        }
        #pragma unroll
        for (int n = 0; n < NF; ++n) {
            const int c = wc * (BN / 2) + n * 16 + lrow;
            bhi[n] = *(const short8*)&BsH[c][kg * 8];
            blo[n] = *(const short8*)&BsL[c][kg * 8];
        }
        #pragma unroll
        for (int m = 0; m < MF; ++m)
            #pragma unroll
            for (int n = 0; n < NF; ++n) {
                acc[m][n] = __builtin_amdgcn_mfma_f32_16x16x32_bf16(ahi[m], bhi[n], acc[m][n], 0, 0, 0);
                acc[m][n] = __builtin_amdgcn_mfma_f32_16x16x32_bf16(ahi[m], blo[n], acc[m][n], 0, 0, 0);
                acc[m][n] = __builtin_amdgcn_mfma_f32_16x16x32_bf16(alo[m], bhi[n], acc[m][n], 0, 0, 0);
            }
        __syncthreads();
    }

    #pragma unroll
    for (int m = 0; m < MF; ++m) {
        #pragma unroll
        for (int n = 0; n < NF; ++n) {
            #pragma unroll
            for (int r = 0; r < 4; ++r) {
                const int row = brow + wr * (BM / 2) + m * 16 + kg * 4 + r;
                const int col = bcol + wc * (BN / 2) + n * 16 + lrow;
                const size_t idx = (size_t)row * ldc + col;
                float v = acc[m][n][r];
                if constexpr (EPI == 1) v += (row == col) ? 1.0f : 0.0f;
                if constexpr (EPI == 2) v = 2.0f * E1[idx] - v;
                C[idx] = v;
                if constexpr (SPLIT) {
                    const HL s = split2(v);
                    Ch[idx] = s.h; Cl[idx] = s.l;
                }
            }
        }
    }
}

// ---------------------------------------------------------------------------
// Big GEMM: flat grid + XCD swizzle + optional split-K, fused A-modes/epilogues.
// AMODE: 0 = f32 A; 1 = pre-split bf16 (Ah/Al); 2 = y-fuse (AE1 + AE2 - 2*clamp(AE2));
//        3 = sum-fuse (AE1 + AE2)  [T split-K partials]
// EPI:   0 = C[cks*ks + idx] = acc (SPLIT optional, KS==1 only for SPLIT)
//        3 = w-update: wn = F1 + Wio - clamp(Wio) - acc;
//            LASTZ ? OutZ = wn - clamp(wn) : Wio = wn
// Grid: NBM*NBN*KS blocks, decode groups same-(m,ks) col-blocks per XCD.
// ---------------------------------------------------------------------------
template<int BM, int BN, int NBM, int NBN, int KS, int AMODE, int EPI, int SPLIT, int LASTZ>
__global__ __launch_bounds__(256)
void gemm_big(const float* __restrict__ A,
              const unsigned short* __restrict__ Ah,
              const unsigned short* __restrict__ Al,
              int lda,
              const float* __restrict__ AE1,
              const float* __restrict__ AE2,
              const unsigned short* __restrict__ Bh,
              const unsigned short* __restrict__ Bl,
              int ldb,
              float* __restrict__ C, int ldc, size_t cks, int Kper,
              const float* __restrict__ F1,
              float* __restrict__ Wio,
              float* __restrict__ OutZ,
              unsigned short* __restrict__ Ch,
              unsigned short* __restrict__ Cl)
{
    constexpr int MF = BM / 32;
    constexpr int NF = BN / 32;
    constexpr int TOT = NBM * NBN * KS;
    static_assert(TOT % 8 == 0, "grid not divisible by XCDs");
    constexpr int SPX = TOT / 8;
    static_assert(SPX % NBN == 0, "slots per XCD not multiple of NBN");
    constexpr int GPX = SPX / NBN;

    __shared__ unsigned short AsH[BM][40], AsL[BM][40];
    __shared__ unsigned short BsH[BN][40], BsL[BN][40];

    const int bid  = blockIdx.x;
    const int xcd  = bid & 7;
    const int slot = bid >> 3;
    const int g    = xcd * GPX + slot / NBN;
    const int n_   = slot % NBN;
    const int m_   = g / KS;
    const int ks   = g % KS;

    const int brow = m_ * BM;
    const int bcol = n_ * BN;
    const int koff = ks * Kper;

    const int tid  = threadIdx.x;
    const int wave = tid >> 6, lane = tid & 63;
    const int wr = wave >> 1, wc = wave & 1;
    const int lrow = lane & 15, kg = lane >> 4;

    f32x4 acc[MF][NF];
    #pragma unroll
    for (int m = 0; m < MF; ++m)
        #pragma unroll
        for (int n = 0; n < NF; ++n)
            #pragma unroll
            for (int q = 0; q < 4; ++q) acc[m][n][q] = 0.0f;

    for (int k0 = 0; k0 < Kper; k0 += 32) {
        constexpr int NPA = BM * 8 / 256;
        #pragma unroll
        for (int p = 0; p < NPA; ++p) {
            const int idx = p * 256 + tid;
            const int row = idx >> 3, k4 = (idx & 7) << 2;
            const size_t gidx = (size_t)(brow + row) * lda + koff + k0 + k4;
            if constexpr (AMODE == 1) {
                *(us4*)&AsH[row][k4] = *(const us4*)(Ah + gidx);
                *(us4*)&AsL[row][k4] = *(const us4*)(Al + gidx);
            } else {
                float4 va;
                if constexpr (AMODE == 0) {
                    va = *(const float4*)(A + gidx);
                } else if constexpr (AMODE == 2) {
                    const float4 a1 = *(const float4*)(AE1 + gidx);
                    const float4 a2 = *(const float4*)(AE2 + gidx);
                    va.x = a1.x + a2.x - 2.0f * clampl(a2.x);
                    va.y = a1.y + a2.y - 2.0f * clampl(a2.y);
                    va.z = a1.z + a2.z - 2.0f * clampl(a2.z);
                    va.w = a1.w + a2.w - 2.0f * clampl(a2.w);
                } else { // AMODE == 3
                    const float4 a1 = *(const float4*)(AE1 + gidx);
                    const float4 a2 = *(const float4*)(AE2 + gidx);
                    va.x = a1.x + a2.x; va.y = a1.y + a2.y;
                    va.z = a1.z + a2.z; va.w = a1.w + a2.w;
                }
                const HL sx = split2(va.x), sy = split2(va.y);
                const HL sz = split2(va.z), sw = split2(va.w);
                us4 h, l;
                h.x = sx.h; l.x = sx.l; h.y = sy.h; l.y = sy.l;
                h.z = sz.h; l.z = sz.l; h.w = sw.h; l.w = sw.l;
                *(us4*)&AsH[row][k4] = h;
                *(us4*)&AsL[row][k4] = l;
            }
        }
        constexpr int NPB = BN * 8 / 256;
        #pragma unroll
        for (int p = 0; p < NPB; ++p) {
            const int idx = p * 256 + tid;
            const int col = idx >> 3, k4 = (idx & 7) << 2;
            const size_t gidx = (size_t)(bcol + col) * ldb + koff + k0 + k4;
            *(us4*)&BsH[col][k4] = *(const us4*)(Bh + gidx);
            *(us4*)&BsL[col][k4] = *(const us4*)(Bl + gidx);
        }
        __syncthreads();

        short8 ahi[MF], alo[MF], bhi[NF], blo[NF];
        #pragma unroll
        for (int m = 0; m < MF; ++m) {
            const int r = wr * (BM / 2) + m * 16 + lrow;
            ahi[m] = *(const short8*)&AsH[r][kg * 8];
            alo[m] = *(const short8*)&AsL[r][kg * 8];
        }
        #pragma unroll
        for (int n = 0; n < NF; ++n) {
            const int c = wc * (BN / 2) + n * 16 + lrow;
            bhi[n] = *(const short8*)&BsH[c][kg * 8];
            blo[n] = *(const short8*)&BsL[c][kg * 8];
        }
        #pragma unroll
        for (int m = 0; m < MF; ++m)
            #pragma unroll
            for (int n = 0; n < NF; ++n) {
                acc[m][n] = __builtin_amdgcn_mfma_f32_16x16x32_bf16(ahi[m], bhi[n], acc[m][n], 0, 0, 0);
                acc[m][n] = __builtin_amdgcn_mfma_f32_16x16x32_bf16(ahi[m], blo[n], acc[m][n], 0, 0, 0);
                acc[m][n] = __builtin_amdgcn_mfma_f32_16x16x32_bf16(alo[m], bhi[n], acc[m][n], 0, 0, 0);
            }
        __syncthreads();
    }

    #pragma unroll
    for (int m = 0; m < MF; ++m) {
        #pragma unroll
        for (int n = 0; n < NF; ++n) {
            #pragma unroll
            for (int r = 0; r < 4; ++r) {
                const int row = brow + wr * (BM / 2) + m * 16 + kg * 4 + r;
                const int col = bcol + wc * (BN / 2) + n * 16 + lrow;
                const size_t idx = (size_t)row * ldc + col;
                const float v = acc[m][n][r];
                if constexpr (EPI == 0) {
                    C[cks * ks + idx] = v;
                    if constexpr (SPLIT) {
                        const HL s = split2(v);
                        Ch[idx] = s.h; Cl[idx] = s.l;
                    }
                } else { // EPI == 3: w-update
                    const float ww = Wio[idx];
                    const float wn_ = F1[idx] + ww - clampl(ww) - v;
                    if constexpr (LASTZ) {
                        OutZ[idx] = wn_ - clampl(wn_);
                    } else {
                        Wio[idx] = wn_;
                    }
                }
            }
        }
    }
}

// Normalize rows of weight (3072 x 768); emit split-bf16 wn and wn^T.
__global__ __launch_bounds__(256)
void rownorm_kernel(const float* __restrict__ W,
                    unsigned short* __restrict__ wnH, unsigned short* __restrict__ wnL,
                    unsigned short* __restrict__ wnTH, unsigned short* __restrict__ wnTL)
{
    __shared__ float red[256];
    const int row = blockIdx.x;
    const int t = threadIdx.x;
    const float* wr = W + (size_t)row * NN_;
    float s = 0.0f;
    for (int k = t; k < NN_; k += 256) { const float w = wr[k]; s += w * w; }
    red[t] = s; __syncthreads();
    for (int off = 128; off > 0; off >>= 1) {
        if (t < off) red[t] += red[t + off];
        __syncthreads();
    }
    const float rn = 1.0f / sqrtf(red[0]);
    for (int k = t; k < NN_; k += 256) {
        const float v = wr[k] * rn;
        const HL s2 = split2(v);
        wnH[(size_t)row * NN_ + k] = s2.h;
        wnL[(size_t)row * NN_ + k] = s2.l;
        wnTH[(size_t)k * MM + row] = s2.h;
        wnTL[(size_t)k * MM + row] = s2.l;
    }
}

__global__ __launch_bounds__(256)
void rowabs_kernel(const float* __restrict__ G, float* __restrict__ rowsum)
{
    __shared__ float red[256];
    const int row = blockIdx.x;
    const int t = threadIdx.x;
    const float* gr = G + (size_t)row * NN_;
    float s = 0.0f;
    for (int k = t; k < NN_; k += 256) s += fabsf(gr[k]);
    red[t] = s; __syncthreads();
    for (int off = 128; off > 0; off >>= 1) {
        if (t < off) red[t] += red[t + off];
        __syncthreads();
    }
    if (t == 0) rowsum[row] = red[0];
}

__global__ __launch_bounds__(256)
void cmax_kernel(const float* __restrict__ rowsum, float* __restrict__ cbuf)
{
    __shared__ float red[256];
    const int t = threadIdx.x;
    float mx = 0.0f;
    for (int k = t; k < NN_; k += 256) mx = fmaxf(mx, rowsum[k]);
    red[t] = mx; __syncthreads();
    for (int off = 128; off > 0; off >>= 1) {
        if (t < off) red[t] = fmaxf(red[t], red[t + off]);
        __syncthreads();
    }
    if (t == 0) cbuf[0] = 2.0f / (1.0f + red[0]);
}

__global__ __launch_bounds__(256)
void initdiag_kernel(float* __restrict__ X, const float* __restrict__ c)
{
    const int idx = blockIdx.x * 256 + threadIdx.x;
    const int p = idx / NN_, q = idx - p * NN_;
    X[idx] = (p == q) ? c[0] : 0.0f;
}

// o = a + b (float4), used to reduce decoded split-K partials
__global__ __launch_bounds__(256)
void add2_kernel(const float* __restrict__ a, const float* __restrict__ b,
                 float* __restrict__ o)
{
    const size_t i = ((size_t)blockIdx.x * 256 + threadIdx.x) * 4;
    const float4 va = *(const float4*)(a + i);
    const float4 vb = *(const float4*)(b + i);
    float4 vo;
    vo.x = va.x + vb.x; vo.y = va.y + vb.y;
    vo.z = va.z + vb.z; vo.w = va.w + vb.w;
    *(float4*)(o + i) = vo;
}

extern "C" void kernel_launch(void* const* d_in, const int* in_sizes, int n_in,
                              void* d_out, int out_size, void* d_ws, size_t ws_size,
                              hipStream_t stream)
{
    const float* x = (const float*)d_in[0];   // (2048, 768)
    const float* w = (const float*)d_in[1];   // (3072, 768)

    float* out = (float*)d_out;
    float* z   = out;                          // (2048, 3072)
    float* dec = out + (size_t)BB * MM;        // (2048, 768)

    char* wsb = (char*)d_ws;
    size_t off = 0;
    auto alloc = [&](size_t bytes) -> void* {
        void* p = wsb + off;
        off += (bytes + 255) & ~(size_t)255;
        return p;
    };
    unsigned short* wnH  = (unsigned short*)alloc((size_t)MM * NN_ * 2);
    unsigned short* wnL  = (unsigned short*)alloc((size_t)MM * NN_ * 2);
    unsigned short* wnTH = (unsigned short*)alloc((size_t)MM * NN_ * 2);
    unsigned short* wnTL = (unsigned short*)alloc((size_t)MM * NN_ * 2);
    float* adotb = (float*)alloc((size_t)BB * MM * 4);
    float* wbuf  = (float*)alloc((size_t)BB * MM * 4);      // ADMM state w
    float* Tp    = (float*)alloc((size_t)2 * BB * NN_ * 4); // split-K partials / RT f32 / dec partials
    float* G     = (float*)alloc((size_t)NN_ * NN_ * 4);
    unsigned short* GH  = (unsigned short*)alloc((size_t)NN_ * NN_ * 2);
    unsigned short* GL  = (unsigned short*)alloc((size_t)NN_ * NN_ * 2);
    float* X0 = (float*)alloc((size_t)NN_ * NN_ * 4);
    float* X1 = (float*)alloc((size_t)NN_ * NN_ * 4);
    float* Yb = (float*)alloc((size_t)NN_ * NN_ * 4);
    unsigned short* YbH = (unsigned short*)alloc((size_t)NN_ * NN_ * 2);
    unsigned short* YbL = (unsigned short*)alloc((size_t)NN_ * NN_ * 2);
    unsigned short* QH  = (unsigned short*)alloc((size_t)NN_ * NN_ * 2);
    unsigned short* QL  = (unsigned short*)alloc((size_t)NN_ * NN_ * 2);
    unsigned short* RTH = (unsigned short*)alloc((size_t)MM * NN_ * 2);
    unsigned short* RTL = (unsigned short*)alloc((size_t)MM * NN_ * 2);
    float* rowsum = (float*)alloc(NN_ * 4);
    float* cbuf   = (float*)alloc(256);

    (void)hipMemsetAsync(wbuf, 0, (size_t)BB * MM * sizeof(float), stream);

    const dim3 blk(256);
    const size_t TPS = (size_t)BB * NN_;   // split-K partial stride

    rownorm_kernel<<<MM, blk, 0, stream>>>(w, wnH, wnL, wnTH, wnTL);

    // adotb = x @ wn^T : M=2048 N=3072 K=768. B[col j][k] = wn[j][k].
    gemm_big<128,64,16,48,1,0,0,0,0><<<768, blk, 0, stream>>>(
        x, nullptr, nullptr, NN_, nullptr, nullptr,
        wnH, wnL, NN_, adotb, MM, 0, NN_,
        nullptr, nullptr, nullptr, nullptr, nullptr);

    // G = wn^T wn + I : 768x768, K=3072 (small template, 144 blocks)
    gemm_mfma<64,64,1,1,1><<<dim3(NN_/64, NN_/64), blk, 0, stream>>>(
        nullptr, wnTH, wnTL, MM, wnTH, wnTL, MM, G, NN_, MM,
        nullptr, GH, GL);

    rowabs_kernel<<<NN_, blk, 0, stream>>>(G, rowsum);
    cmax_kernel<<<1, blk, 0, stream>>>(rowsum, cbuf);
    initdiag_kernel<<<(NN_ * NN_) / 256, blk, 0, stream>>>(X0, cbuf);

    // Newton-Schulz: X <- 2X - X G X, 9 iterations
    float* Xc = X0;
    float* Xn = X1;
    for (int it = 0; it < 9; ++it) {
        gemm_mfma<64,64,0,0,1><<<dim3(NN_/64, NN_/64), blk, 0, stream>>>(
            Xc, nullptr, nullptr, NN_, GH, GL, NN_, Yb, NN_, NN_,
            nullptr, YbH, YbL);
        gemm_mfma<64,64,0,2,1><<<dim3(NN_/64, NN_/64), blk, 0, stream>>>(
            Xc, nullptr, nullptr, NN_, YbH, YbL, NN_, Xn, NN_, NN_,
            Xc, QH, QL);
        float* t = Xc; Xc = Xn; Xn = t;
    }
    // QH/QL = split(G^{-1})

    // RT = wn @ Ginv : M=3072 N=768 K=768 (RT[j][k] = R[k][j], R = Ginv wn^T)
    gemm_big<128,64,24,12,1,1,0,1,0><<<288, blk, 0, stream>>>(
        nullptr, wnH, wnL, NN_, nullptr, nullptr,
        QH, QL, NN_, Tp, NN_, 0, NN_,
        nullptr, nullptr, nullptr, RTH, RTL);

    // ADMM loop: 20 iterations of
    //   T  = (adotb + w - 2*clamp(w)) @ wn          (split-K=2)
    //   w <- adotb + w - clamp(w) - (T0+T1) @ RT^T  (last iter: z = shrink(w))
    for (int it = 0; it < 20; ++it) {
        gemm_big<128,64,16,12,2,2,0,0,0><<<384, blk, 0, stream>>>(
            nullptr, nullptr, nullptr, MM, adotb, wbuf,
            wnTH, wnTL, MM, Tp, NN_, TPS, MM / 2,
            nullptr, nullptr, nullptr, nullptr, nullptr);
        if (it < 19) {
            gemm_big<128,64,16,48,1,3,3,0,0><<<768, blk, 0, stream>>>(
                nullptr, nullptr, nullptr, NN_, Tp, Tp + TPS,
                RTH, RTL, NN_, nullptr, MM, 0, NN_,
                adotb, wbuf, nullptr, nullptr, nullptr);
        } else {
            gemm_big<128,64,16,48,1,3,3,0,1><<<768, blk, 0, stream>>>(
                nullptr, nullptr, nullptr, NN_, Tp, Tp + TPS,
                RTH, RTL, NN_, nullptr, MM, 0, NN_,
                adotb, wbuf, z, nullptr, nullptr);
        }
    }

    // decoded = z @ wn : M=2048 N=768 K=3072, split-K=2 into Tp, then reduce
    gemm_big<128,64,16,12,2,0,0,0,0><<<384, blk, 0, stream>>>(
        z, nullptr, nullptr, MM, nullptr, nullptr,
        wnTH, wnTL, MM, Tp, NN_, TPS, MM / 2,
        nullptr, nullptr, nullptr, nullptr, nullptr);
    add2_kernel<<<(BB * NN_ / 4) / 256, blk, 0, stream>>>(Tp, Tp + TPS, dec);
}